// Round 10
// baseline (516.091 us; speedup 1.0000x reference)
//
#include <hip/hip_runtime.h>

typedef unsigned short ushort_t;
typedef __bf16 bf16_t;
typedef __bf16 bf16x8_b __attribute__((ext_vector_type(8)));
typedef bf16x8_b __attribute__((may_alias)) bf16x8;
typedef unsigned short u16x8_b __attribute__((ext_vector_type(8)));
typedef u16x8_b __attribute__((may_alias)) u16x8;
typedef unsigned short u16x4_b __attribute__((ext_vector_type(4)));
typedef u16x4_b __attribute__((may_alias)) u16x4;
typedef unsigned int u32x4_b __attribute__((ext_vector_type(4)));
typedef u32x4_b __attribute__((may_alias)) u32x4;
typedef float floatx4 __attribute__((ext_vector_type(4)));

__device__ __forceinline__ float bf2f(ushort_t h) {
    union { unsigned int u; float f; } v; v.u = ((unsigned int)h) << 16; return v.f;
}
__device__ __forceinline__ ushort_t f2bf(float f) {
    union { float f; unsigned int u; } v; v.f = f;
    unsigned int u = v.u;
    unsigned int r = (u + 0x7FFFu + ((u >> 16) & 1u)) >> 16;
    return (ushort_t)r;
}

// Async global->LDS DMA, 16B per lane. Dest must be wave-uniform base; HW adds
// lane*16. Completion tracked by vmcnt; __syncthreads() drains it.
__device__ __forceinline__ void glds16(const ushort_t* g, ushort_t* l) {
    __builtin_amdgcn_global_load_lds(
        (const __attribute__((address_space(1))) unsigned int*)g,
        (__attribute__((address_space(3))) unsigned int*)l, 16, 0, 0);
}

// ---------------------------------------------------------------------------
// Input dtype sniff: flag=1 means fp32 inputs.
// ---------------------------------------------------------------------------
__global__ __launch_bounds__(256) void detect_dtype(
    const unsigned int* __restrict__ x, int* __restrict__ flag)
{
    __shared__ int cnt;
    if (threadIdx.x == 0) cnt = 0;
    __syncthreads();
    int c = 0;
    for (int i = threadIdx.x; i < 512; i += 256) {
        unsigned int w = x[i];
        unsigned int e = (w >> 7) & 0xFFu;
        if (e >= 0x70u && e <= 0x8Fu) ++c;
    }
    atomicAdd(&cnt, c);
    __syncthreads();
    if (threadIdx.x == 0) *flag = (cnt < 256) ? 1 : 0;
}

// ---------------------------------------------------------------------------
// Transpose+convert 6 weights [1024,1024] -> WT[z][n][k] = bf16(W[k][n])
// ---------------------------------------------------------------------------
__global__ __launch_bounds__(256) void conv_weights(
    const void* __restrict__ w0, const void* __restrict__ w1,
    const void* __restrict__ w2, const void* __restrict__ w3,
    const void* __restrict__ w4, const void* __restrict__ w5,
    ushort_t* __restrict__ WT, const int* __restrict__ flag)
{
    __shared__ ushort_t t[64][65];
    const int z = blockIdx.z;
    const void* src = (z == 0) ? w0 : (z == 1) ? w1 : (z == 2) ? w2
                    : (z == 3) ? w3 : (z == 4) ? w4 : w5;
    const bool isf = (*flag != 0);
    ushort_t* dst = WT + (size_t)z * 1024 * 1024;
    const int x0 = blockIdx.x * 64, y0 = blockIdx.y * 64;
    const int tx = threadIdx.x & 63, ty0 = threadIdx.x >> 6;
#pragma unroll
    for (int r = 0; r < 16; ++r) {
        int ty = ty0 * 16 + r;
        size_t idx = (size_t)(y0 + ty) * 1024 + x0 + tx;
        t[ty][tx] = isf ? f2bf(((const float*)src)[idx]) : ((const ushort_t*)src)[idx];
    }
    __syncthreads();
#pragma unroll
    for (int r = 0; r < 16; ++r) {
        int ty = ty0 * 16 + r;
        dst[(size_t)(x0 + ty) * 1024 + y0 + tx] = t[tx][ty];
    }
}

__global__ __launch_bounds__(256) void conv_bout(
    const void* __restrict__ bout, ushort_t* __restrict__ dst,
    const int* __restrict__ flag)
{
    const bool isf = (*flag != 0);
    for (int i = threadIdx.x; i < 1024; i += 256)
        dst[i] = isf ? f2bf(((const float*)bout)[i]) : ((const ushort_t*)bout)[i];
}

// ---------------------------------------------------------------------------
// Convert a slice of {h_t,h_a,h_v} to bf16 in ws (h_hyper read raw later).
// ---------------------------------------------------------------------------
__global__ __launch_bounds__(256) void conv_act(
    const void* __restrict__ h_t, const void* __restrict__ h_a,
    const void* __restrict__ h_v,
    long off, ushort_t* __restrict__ ActC, long tstride,
    const int* __restrict__ flag)
{
    const int z = blockIdx.y;
    const void* s = (z == 0) ? h_t : (z == 1) ? h_a : h_v;
    const size_t e8 = ((size_t)blockIdx.x * 256 + threadIdx.x) * 8;
    ushort_t* dst = ActC + (size_t)z * tstride + e8;
    if (*flag) {
        const float* f = (const float*)s + off + e8;
        u32x4 o;
#pragma unroll
        for (int j = 0; j < 4; ++j) {
            unsigned int lo = f2bf(f[2 * j]);
            unsigned int hi = f2bf(f[2 * j + 1]);
            o[j] = lo | (hi << 16);
        }
        *(u32x4*)dst = o;
    } else {
        const ushort_t* b = (const ushort_t*)s + off + e8;
        *(u32x4*)dst = *(const u32x4*)b;
    }
}

// ---------------------------------------------------------------------------
// Core GEMM: C[M,1024] = A[M,1024] @ B, BT[1024,1024] given. Tile 128x128.
// Staging via global_load_lds width=16. Grid: x = m-tile, y = n-tile (T1).
// tr=true (V projections): transposed output VT[b][d][tok] written COALESCED
// via an LDS bounce. R9 BUG FIXED: u16x8 is 8 ELEMENTS (16B), so each thread
// must issue 4 stores to cover its 32-element segment — R9 issued 2, leaving
// tokens 8-15/24-31 (mod 32) of every V^T row unwritten (absmax 0.32).
// Address mapping itself verified identical to R8's per-element ti formula.
// ---------------------------------------------------------------------------
__device__ __forceinline__ void gemm_core(
    const ushort_t* __restrict__ A, const ushort_t* __restrict__ BT,
    void* __restrict__ C, size_t ooff, bool f32o, bool tr,
    const void* __restrict__ addraw, long aoff,
    const ushort_t* __restrict__ bias, bool isf)
{
    constexpr int K = 1024, N = 1024;
    // smem hosts As(4096) + Bs(4096) during K-loop; tr-epilogue reuses it as
    // a 64 x 136 bounce tile (8704 elem).
    __shared__ __align__(16) ushort_t smem[64 * 136];
    ushort_t* As = smem;           // [m][k] linear, 128*32
    ushort_t* Bs = smem + 4096;    // [n][k] linear, 128*32
    const int tid = threadIdx.x;
    const int w = tid >> 6, lane = tid & 63;
    const int g = lane >> 4, c = lane & 15;
    const int m0 = blockIdx.x * 128, n0 = blockIdx.y * 128;   // swapped (T1)
    const int wm = (w >> 1) * 64, wn = (w & 1) * 64;

    const int srow = w * 32 + (lane >> 2);
    const int scol = (lane & 3) * 8;
    const ushort_t* Ag = A + (size_t)(m0 + srow) * K + scol;
    const ushort_t* Bg = BT + (size_t)(n0 + srow) * K + scol;
    ushort_t* AsW = As + w * 1024;
    ushort_t* BsW = Bs + w * 1024;

    floatx4 acc[4][4];
#pragma unroll
    for (int i = 0; i < 4; ++i)
#pragma unroll
        for (int j = 0; j < 4; ++j) acc[i][j] = (floatx4)0.0f;

    for (int k0 = 0; k0 < K; k0 += 32) {
        __syncthreads();
        glds16(Ag + k0,          AsW);
        glds16(Ag + k0 + 16 * K, AsW + 512);
        glds16(Bg + k0,          BsW);
        glds16(Bg + k0 + 16 * K, BsW + 512);
        __syncthreads();
        bf16x8 af[4], bfr[4];
#pragma unroll
        for (int i = 0; i < 4; ++i)
            af[i] = *(const bf16x8*)&As[(wm + i * 16 + c) * 32 + g * 8];
#pragma unroll
        for (int j = 0; j < 4; ++j)
            bfr[j] = *(const bf16x8*)&Bs[(wn + j * 16 + c) * 32 + g * 8];
#pragma unroll
        for (int i = 0; i < 4; ++i)
#pragma unroll
            for (int j = 0; j < 4; ++j)
                acc[i][j] = __builtin_amdgcn_mfma_f32_16x16x32_bf16(
                    af[i], bfr[j], acc[i][j], 0, 0, 0);
    }

    if (tr) {
        // ---- coalesced transposed store via LDS bounce ----
        // Block output: tokens [m0, m0+128), dims [n0, n0+128).
        ushort_t* VT = (ushort_t*)C + ((size_t)(m0 >> 10) << 20) + (m0 & 1023);
        const int myh = (w & 1);     // which 64-dim half this wave produced
        __syncthreads();             // K-loop fragment reads done
#pragma unroll
        for (int h = 0; h < 2; ++h) {
            if (myh == h) {
                // stage: T[d_local = j*16+c][tok = wm + i*16 + g*4 + r]
#pragma unroll
                for (int i = 0; i < 4; ++i)
#pragma unroll
                    for (int j = 0; j < 4; ++j) {
                        u16x4 o4;
#pragma unroll
                        for (int r = 0; r < 4; ++r) o4[r] = f2bf(acc[i][j][r]);
                        *(u16x4*)&smem[(j * 16 + c) * 136 + wm + i * 16 + g * 4] = o4;
                    }
            }
            __syncthreads();
            // write out: 256 threads x 32 elems = 64 rows x 128 tok;
            // 4 x u16x8 (8 elems each) per thread = full 32-elem coverage
            {
                const int row = tid >> 2;            // 0..63
                const int seg = (tid & 3) * 32;      // 0,32,64,96
                const size_t drow = (size_t)(n0 + h * 64 + row) * 1024;
#pragma unroll
                for (int k = 0; k < 4; ++k)
                    *(u16x8*)&VT[drow + seg + k * 8] =
                        *(const u16x8*)&smem[row * 136 + seg + k * 8];
            }
            __syncthreads();
        }
        return;
    }

#pragma unroll
    for (int i = 0; i < 4; ++i) {
#pragma unroll
        for (int j = 0; j < 4; ++j) {
            const int gc = n0 + wn + j * 16 + c;
            const int gr0 = m0 + wm + i * 16 + g * 4;
#pragma unroll
            for (int r = 0; r < 4; ++r) {
                const int gr = gr0 + r;
                float v = acc[i][j][r];
                if (addraw) {
                    const size_t ai = (size_t)aoff + (size_t)gr * N + gc;
                    const float av = isf ? ((const float*)addraw)[ai]
                                         : bf2f(((const ushort_t*)addraw)[ai]);
                    v += av + bf2f(bias[gc]);
                }
                const size_t idx = ooff + (size_t)gr * N + gc;
                if (f32o) ((float*)C)[idx] = v;
                else      ((ushort_t*)C)[idx] = f2bf(v);
            }
        }
    }
}

__global__ __launch_bounds__(256) void gemm_proj(
    const ushort_t* __restrict__ ActC, const ushort_t* __restrict__ WT,
    ushort_t* __restrict__ Pbuf, long astride, long pstride)
{
    const int z = blockIdx.z;
    const int asel = (z == 0) ? 0 : (z <= 2 ? 1 : 2);
    // WT order: 0 Wq, 1 Wk_ta, 2 Wk_tv, 3 Wv_ta, 4 Wv_tv, 5 Wout
    const int wsel = (z == 2) ? 3 : ((z == 3) ? 2 : z);
    const bool tr = (z == 2) || (z == 4);   // V projections -> transposed
    gemm_core(ActC + (size_t)asel * astride,
              WT + (size_t)wsel * 1024 * 1024,
              Pbuf + (size_t)z * pstride, 0, false, tr,
              nullptr, 0, nullptr, false);
}

__global__ __launch_bounds__(256) void gemm_out(
    const ushort_t* __restrict__ OutSum, const ushort_t* __restrict__ WoutT,
    const void* __restrict__ hyper_raw, long aoff,
    const ushort_t* __restrict__ boutC,
    void* __restrict__ out, long ooff, const int* __restrict__ flag)
{
    const bool isf = (*flag != 0);
    gemm_core(OutSum, WoutT, out, (size_t)ooff, isf, false,
              hyper_raw, aoff, boutC, isf);
}

// ---------------------------------------------------------------------------
// Fused dual-stream MFMA flash attention — EXACT R8 code (passed @167.5us):
//  - swapped QK^T: lane-local softmax rows; shfl 64 -> 16 per kt
//  - Ps stride 68 (measured zero-conflict); b64 P-writes via f2bf/u16x4
//    (R9's native-cast variant reverted pending isolated A/B — one delta
//    per round after a failure)
//  - T13 defer-max THR=8
//  - V consumed from VT (d-major from gemm_proj)
// ---------------------------------------------------------------------------
__global__ __launch_bounds__(512) void attn_fused(
    const ushort_t* __restrict__ Qb,
    const ushort_t* __restrict__ Kta, const ushort_t* __restrict__ Vta,
    const ushort_t* __restrict__ Ktv, const ushort_t* __restrict__ Vtv,
    ushort_t* __restrict__ Osum)
{
    const int h = blockIdx.x, qb = blockIdx.y, lb = blockIdx.z;
    const int tid = threadIdx.x, w = tid >> 6, lane = tid & 63;
    const int g = lane >> 4, c = lane & 15;

    __shared__ __align__(16) ushort_t Ks[2][64 * 68];   // K tiles [j][d]
    __shared__ __align__(16) ushort_t Vt[2][64 * 68];   // V^T tiles [d][j]
    __shared__ __align__(16) ushort_t Ps[8][16 * 68];   // per-wave P [q][j]

    const float qscale = 0.125f * 1.44269504f;  // SCALE * log2(e)
    const size_t hcol = (size_t)h * 64;
    const size_t kbase = (size_t)lb * 1024;

    // staging coords: 512 threads cover 64 rows x 64 cols in one shot
    const int sj = tid >> 3;            // 0..63
    const int sd = (tid & 7) * 8;       // 0..56

    const ushort_t* Kp[2] = { Kta, Ktv };
    const ushort_t* Vv[2] = { Vta, Vtv };
    // VT row base for this (lb, h): VT[lb][hcol + sj][*]
    const size_t vrow = (size_t)lb * 1048576 + (hcol + sj) * 1024;

    // ---- prefetch kt=0 tiles into registers (in flight during Q setup)
    u32x4 pk[2], pv[2];
#pragma unroll
    for (int s = 0; s < 2; ++s) {
        pk[s] = *(const u32x4*)(Kp[s] + (kbase + sj) * 1024 + hcol + sd);
        pv[s] = *(const u32x4*)(Vv[s] + vrow + sd);
    }

    // ---- stage Q (128 rows) through Ks[0..1]; hoist pre-scaled fragments
    bf16x8 aq[2];
    {
        const size_t qrow0 = kbase + (size_t)qb * 128;
#pragma unroll
        for (int r = 0; r < 2; ++r)
            *(u32x4*)&Ks[r][sj * 68 + sd] =
                *(const u32x4*)(Qb + (qrow0 + r * 64 + sj) * 1024 + hcol + sd);
        __syncthreads();
        const int qbuf = w >> 2, qrow = (w & 3) * 16;
#pragma unroll
        for (int dh = 0; dh < 2; ++dh) {
            u16x8 raw = *(const u16x8*)&Ks[qbuf][(qrow + c) * 68 + dh * 32 + g * 8];
            u16x8 sc;
#pragma unroll
            for (int e = 0; e < 8; ++e) sc[e] = f2bf(bf2f(raw[e]) * qscale);
            aq[dh] = __builtin_bit_cast(bf16x8_b, (u16x8_b)sc);
        }
    }

    floatx4 O[2][4];
    float m[2], l[2];
#pragma unroll
    for (int s = 0; s < 2; ++s) {
#pragma unroll
        for (int dt = 0; dt < 4; ++dt) O[s][dt] = (floatx4)0.0f;
        m[s] = -1e30f; l[s] = 0.0f;
    }

    for (int kt = 0; kt < 16; ++kt) {
        __syncthreads();  // previous tile's LDS reads complete
#pragma unroll
        for (int s = 0; s < 2; ++s) {
            *(u32x4*)&Ks[s][sj * 68 + sd] = pk[s];
            *(u32x4*)&Vt[s][sj * 68 + sd] = pv[s];
        }
        if (kt < 15) {
            const size_t krow0 = kbase + (size_t)(kt + 1) * 64;
#pragma unroll
            for (int s = 0; s < 2; ++s) {
                pk[s] = *(const u32x4*)(Kp[s] + (krow0 + sj) * 1024 + hcol + sd);
                pv[s] = *(const u32x4*)(Vv[s] + vrow + (kt + 1) * 64 + sd);
            }
        }
        __syncthreads();  // tiles visible to all waves

        // ---- QK^T (swapped): S^T[j][q], both streams
        floatx4 S[2][4];
#pragma unroll
        for (int s = 0; s < 2; ++s)
#pragma unroll
            for (int jt = 0; jt < 4; ++jt) S[s][jt] = (floatx4)0.0f;
        __builtin_amdgcn_s_setprio(1);
#pragma unroll
        for (int s = 0; s < 2; ++s)
#pragma unroll
            for (int dh = 0; dh < 2; ++dh)
#pragma unroll
                for (int jt = 0; jt < 4; ++jt) {
                    bf16x8 bk = *(const bf16x8*)&Ks[s][(jt * 16 + c) * 68 + dh * 32 + g * 8];
                    S[s][jt] = __builtin_amdgcn_mfma_f32_16x16x32_bf16(
                        bk, aq[dh], S[s][jt], 0, 0, 0);
                }
        __builtin_amdgcn_s_setprio(0);

        // ---- per stream: lane-local softmax (defer-max) -> Ps (b64) -> PV
#pragma unroll
        for (int s = 0; s < 2; ++s) {
            // tile max over the 16 lane-local j-values + cross-g reduce
            float mx0 = fmaxf(fmaxf(S[s][0][0], S[s][0][1]),
                              fmaxf(S[s][0][2], S[s][0][3]));
            float mx1 = fmaxf(fmaxf(S[s][1][0], S[s][1][1]),
                              fmaxf(S[s][1][2], S[s][1][3]));
            float mx2 = fmaxf(fmaxf(S[s][2][0], S[s][2][1]),
                              fmaxf(S[s][2][2], S[s][2][3]));
            float mx3 = fmaxf(fmaxf(S[s][3][0], S[s][3][1]),
                              fmaxf(S[s][3][2], S[s][3][3]));
            float mx = fmaxf(fmaxf(mx0, mx1), fmaxf(mx2, mx3));
            mx = fmaxf(mx, __shfl_xor(mx, 16));
            mx = fmaxf(mx, __shfl_xor(mx, 32));

            // T13 defer-max: only rescale when the tile max grew past m+8.
            const bool need = !__all(mx - m[s] <= 8.0f);
            float mn = m[s];
            if (need) mn = fmaxf(m[s], mx);

            float rs = 0.0f;
#pragma unroll
            for (int jt = 0; jt < 4; ++jt) {
                u16x4 pp;
#pragma unroll
                for (int r = 0; r < 4; ++r) {
                    const float p = __builtin_amdgcn_exp2f(S[s][jt][r] - mn);
                    rs += p;
                    pp[r] = f2bf(p);
                }
                *(u16x4*)&Ps[w][c * 68 + jt * 16 + g * 4] = pp;
            }
            rs += __shfl_xor(rs, 16);
            rs += __shfl_xor(rs, 32);

            if (need) {
                const float al = __builtin_amdgcn_exp2f(m[s] - mn);
                m[s] = mn;
                l[s] = l[s] * al + rs;
                float alq[4];
#pragma unroll
                for (int r = 0; r < 4; ++r) alq[r] = __shfl(al, g * 4 + r);
#pragma unroll
                for (int dt = 0; dt < 4; ++dt)
#pragma unroll
                    for (int r = 0; r < 4; ++r) O[s][dt][r] *= alq[r];
            } else {
                l[s] += rs;
            }

            // PV: A = P[q=c][j-slice], B = V^T[d=c][j-slice]
#pragma unroll
            for (int jh = 0; jh < 2; ++jh) {
                bf16x8 ap = *(const bf16x8*)&Ps[w][c * 68 + jh * 32 + g * 8];
                __builtin_amdgcn_s_setprio(1);
#pragma unroll
                for (int dt = 0; dt < 4; ++dt) {
                    bf16x8 bv = *(const bf16x8*)&Vt[s][(dt * 16 + c) * 68
                                                      + jh * 32 + g * 8];
                    O[s][dt] = __builtin_amdgcn_mfma_f32_16x16x32_bf16(
                        ap, bv, O[s][dt], 0, 0, 0);
                }
                __builtin_amdgcn_s_setprio(0);
            }
        }
    }

    // ---- epilogue: transport l to O-row layout; Osum = O_ta/l + O_tv/l
    float lq0[4], lq1[4];
#pragma unroll
    for (int r = 0; r < 4; ++r) {
        lq0[r] = __shfl(l[0], g * 4 + r);
        lq1[r] = __shfl(l[1], g * 4 + r);
    }
    const size_t orow0 = kbase + (size_t)qb * 128 + w * 16;
#pragma unroll
    for (int dt = 0; dt < 4; ++dt)
#pragma unroll
        for (int r = 0; r < 4; ++r) {
            const float v = O[0][dt][r] / lq0[r] + O[1][dt][r] / lq1[r];
            Osum[(orow0 + g * 4 + r) * 1024 + hcol + dt * 16 + c] = f2bf(v);
        }
}

// ---------------------------------------------------------------------------
extern "C" void kernel_launch(void* const* d_in, const int* in_sizes, int n_in,
                              void* d_out, int out_size, void* d_ws, size_t ws_size,
                              hipStream_t stream)
{
    const void* h_t     = d_in[0];
    const void* h_a     = d_in[1];
    const void* h_v     = d_in[2];
    const void* h_hyper = d_in[3];
    const void* Wq      = d_in[4];
    const void* Wk_ta   = d_in[5];
    const void* Wk_tv   = d_in[6];
    const void* Wv_ta   = d_in[7];
    const void* Wv_tv   = d_in[8];
    const void* Wout    = d_in[9];
    const void* bout    = d_in[10];

    constexpr size_t MEG = (size_t)1024 * 1024;
    // header: flag at elem 0, boutC at elem 1024; payload starts at elem 4096
    int*      flag  = (int*)d_ws;
    ushort_t* boutC = (ushort_t*)d_ws + 1024;
    ushort_t* WT    = (ushort_t*)d_ws + 4096;

    detect_dtype<<<1, 256, 0, stream>>>((const unsigned int*)h_t, flag);
    conv_weights<<<dim3(16, 16, 6), 256, 0, stream>>>(
        Wq, Wk_ta, Wk_tv, Wv_ta, Wv_tv, Wout, WT, flag);
    conv_bout<<<1, 256, 0, stream>>>(bout, boutC, flag);

    // merged path needs: 4096 + 6M(WT) + 24M(ActC) + 40M(Pbuf) elements
    const size_t need_merged = (4096 + 70 * MEG) * sizeof(ushort_t);

    if (ws_size >= need_merged) {
        // ---- single pass over all 8 batches ----
        ushort_t* ActC = WT + 6 * MEG;          // 3 x 8M (h_t,h_a,h_v bf16)
        ushort_t* Pbuf = ActC + 24 * MEG;       // 5 x 8M projections
        ushort_t* OSg  = ActC;                  // alias: ActC dead after proj

        conv_act<<<dim3(4096, 3), 256, 0, stream>>>(
            h_t, h_a, h_v, 0, ActC, (long)(8 * MEG), flag);
        gemm_proj<<<dim3(64, 8, 5), 256, 0, stream>>>(
            ActC, WT, Pbuf, (long)(8 * MEG), (long)(8 * MEG));
        attn_fused<<<dim3(16, 8, 8), 512, 0, stream>>>(
            Pbuf,
            Pbuf + 8 * MEG,  Pbuf + 16 * MEG,
            Pbuf + 24 * MEG, Pbuf + 32 * MEG,
            OSg);
        gemm_out<<<dim3(64, 8), 256, 0, stream>>>(
            OSg, WT + 5 * MEG, h_hyper, 0, boutC, d_out, 0, flag);
    } else {
        // ---- fallback: 4 groups of 2 batches (same kernels, smaller grid) ----
        ushort_t* ActC = WT + 6 * MEG;          // 3 x 2M
        ushort_t* Pbuf = ActC + 6 * MEG;        // 5 x 2M
        ushort_t* OSg  = ActC;                  // alias: ActC dead after proj
        const long GSTRIDE = 2 * 1024 * 1024;
        for (int grp = 0; grp < 4; ++grp) {
            const long off = (long)grp * GSTRIDE;
            conv_act<<<dim3(1024, 3), 256, 0, stream>>>(
                h_t, h_a, h_v, off, ActC, (long)(2 * MEG), flag);
            gemm_proj<<<dim3(16, 8, 5), 256, 0, stream>>>(
                ActC, WT, Pbuf, (long)(2 * MEG), (long)(2 * MEG));
            attn_fused<<<dim3(16, 8, 2), 512, 0, stream>>>(
                Pbuf,
                Pbuf + 2 * MEG, Pbuf + 4 * MEG,
                Pbuf + 6 * MEG, Pbuf + 8 * MEG,
                OSg);
            gemm_out<<<dim3(16, 8), 256, 0, stream>>>(
                OSg, WT + 5 * MEG, h_hyper, off, boutC, d_out, off, flag);
        }
    }
}

// Round 11
// 504.261 us; speedup vs baseline: 1.0235x; 1.0235x over previous
//
#include <hip/hip_runtime.h>

typedef unsigned short ushort_t;
typedef __bf16 bf16_t;
typedef __bf16 bf16x8_b __attribute__((ext_vector_type(8)));
typedef bf16x8_b __attribute__((may_alias)) bf16x8;
typedef __bf16 bf16x4_b __attribute__((ext_vector_type(4)));
typedef bf16x4_b __attribute__((may_alias)) bf16x4;
typedef unsigned short u16x8_b __attribute__((ext_vector_type(8)));
typedef u16x8_b __attribute__((may_alias)) u16x8;
typedef unsigned short u16x4_b __attribute__((ext_vector_type(4)));
typedef u16x4_b __attribute__((may_alias)) u16x4;
typedef unsigned int u32x4_b __attribute__((ext_vector_type(4)));
typedef u32x4_b __attribute__((may_alias)) u32x4;
typedef float floatx4 __attribute__((ext_vector_type(4)));

__device__ __forceinline__ float bf2f(ushort_t h) {
    union { unsigned int u; float f; } v; v.u = ((unsigned int)h) << 16; return v.f;
}
__device__ __forceinline__ ushort_t f2bf(float f) {
    union { float f; unsigned int u; } v; v.f = f;
    unsigned int u = v.u;
    unsigned int r = (u + 0x7FFFu + ((u >> 16) & 1u)) >> 16;
    return (ushort_t)r;
}

// Async global->LDS DMA, 16B per lane. Dest must be wave-uniform base; HW adds
// lane*16. Completion tracked by vmcnt; __syncthreads() drains it.
__device__ __forceinline__ void glds16(const ushort_t* g, ushort_t* l) {
    __builtin_amdgcn_global_load_lds(
        (const __attribute__((address_space(1))) unsigned int*)g,
        (__attribute__((address_space(3))) unsigned int*)l, 16, 0, 0);
}

// ---------------------------------------------------------------------------
// Input dtype sniff: flag=1 means fp32 inputs.
// ---------------------------------------------------------------------------
__global__ __launch_bounds__(256) void detect_dtype(
    const unsigned int* __restrict__ x, int* __restrict__ flag)
{
    __shared__ int cnt;
    if (threadIdx.x == 0) cnt = 0;
    __syncthreads();
    int c = 0;
    for (int i = threadIdx.x; i < 512; i += 256) {
        unsigned int w = x[i];
        unsigned int e = (w >> 7) & 0xFFu;
        if (e >= 0x70u && e <= 0x8Fu) ++c;
    }
    atomicAdd(&cnt, c);
    __syncthreads();
    if (threadIdx.x == 0) *flag = (cnt < 256) ? 1 : 0;
}

// ---------------------------------------------------------------------------
// Transpose+convert 6 weights [1024,1024] -> WT[z][n][k] = bf16(W[k][n])
// ---------------------------------------------------------------------------
__global__ __launch_bounds__(256) void conv_weights(
    const void* __restrict__ w0, const void* __restrict__ w1,
    const void* __restrict__ w2, const void* __restrict__ w3,
    const void* __restrict__ w4, const void* __restrict__ w5,
    ushort_t* __restrict__ WT, const int* __restrict__ flag)
{
    __shared__ ushort_t t[64][65];
    const int z = blockIdx.z;
    const void* src = (z == 0) ? w0 : (z == 1) ? w1 : (z == 2) ? w2
                    : (z == 3) ? w3 : (z == 4) ? w4 : w5;
    const bool isf = (*flag != 0);
    ushort_t* dst = WT + (size_t)z * 1024 * 1024;
    const int x0 = blockIdx.x * 64, y0 = blockIdx.y * 64;
    const int tx = threadIdx.x & 63, ty0 = threadIdx.x >> 6;
#pragma unroll
    for (int r = 0; r < 16; ++r) {
        int ty = ty0 * 16 + r;
        size_t idx = (size_t)(y0 + ty) * 1024 + x0 + tx;
        t[ty][tx] = isf ? f2bf(((const float*)src)[idx]) : ((const ushort_t*)src)[idx];
    }
    __syncthreads();
#pragma unroll
    for (int r = 0; r < 16; ++r) {
        int ty = ty0 * 16 + r;
        dst[(size_t)(x0 + ty) * 1024 + y0 + tx] = t[tx][ty];
    }
}

__global__ __launch_bounds__(256) void conv_bout(
    const void* __restrict__ bout, ushort_t* __restrict__ dst,
    const int* __restrict__ flag)
{
    const bool isf = (*flag != 0);
    for (int i = threadIdx.x; i < 1024; i += 256)
        dst[i] = isf ? f2bf(((const float*)bout)[i]) : ((const ushort_t*)bout)[i];
}

// ---------------------------------------------------------------------------
// Convert a slice of {h_t,h_a,h_v} to bf16 in ws (h_hyper read raw later).
// ---------------------------------------------------------------------------
__global__ __launch_bounds__(256) void conv_act(
    const void* __restrict__ h_t, const void* __restrict__ h_a,
    const void* __restrict__ h_v,
    long off, ushort_t* __restrict__ ActC, long tstride,
    const int* __restrict__ flag)
{
    const int z = blockIdx.y;
    const void* s = (z == 0) ? h_t : (z == 1) ? h_a : h_v;
    const size_t e8 = ((size_t)blockIdx.x * 256 + threadIdx.x) * 8;
    ushort_t* dst = ActC + (size_t)z * tstride + e8;
    if (*flag) {
        const float* f = (const float*)s + off + e8;
        u32x4 o;
#pragma unroll
        for (int j = 0; j < 4; ++j) {
            unsigned int lo = f2bf(f[2 * j]);
            unsigned int hi = f2bf(f[2 * j + 1]);
            o[j] = lo | (hi << 16);
        }
        *(u32x4*)dst = o;
    } else {
        const ushort_t* b = (const ushort_t*)s + off + e8;
        *(u32x4*)dst = *(const u32x4*)b;
    }
}

// ---------------------------------------------------------------------------
// Core GEMM: C[M,1024] = A[M,1024] @ B, BT[1024,1024] given. Tile 128x128.
// Staging via global_load_lds width=16. Grid: x = m-tile, y = n-tile (T1).
// tr=true (V projections): direct transposed u16x4 stores VT[b][gc][n] —
// R8-exact. (R10 measured: LDS-bounce coalescing was a 12us REGRESSION —
// the scattered 8B stores are L2-absorbed since attn re-reads V^T soon after;
// the bounce only added barriers. Keep the direct form.)
// ---------------------------------------------------------------------------
__device__ __forceinline__ void gemm_core(
    const ushort_t* __restrict__ A, const ushort_t* __restrict__ BT,
    void* __restrict__ C, size_t ooff, bool f32o, bool tr,
    const void* __restrict__ addraw, long aoff,
    const ushort_t* __restrict__ bias, bool isf)
{
    constexpr int K = 1024, N = 1024;
    __shared__ __align__(16) ushort_t As[128 * 32];  // [m][k] linear
    __shared__ __align__(16) ushort_t Bs[128 * 32];  // [n][k] linear
    const int tid = threadIdx.x;
    const int w = tid >> 6, lane = tid & 63;
    const int g = lane >> 4, c = lane & 15;
    const int m0 = blockIdx.x * 128, n0 = blockIdx.y * 128;   // swapped (T1)
    const int wm = (w >> 1) * 64, wn = (w & 1) * 64;

    const int srow = w * 32 + (lane >> 2);
    const int scol = (lane & 3) * 8;
    const ushort_t* Ag = A + (size_t)(m0 + srow) * K + scol;
    const ushort_t* Bg = BT + (size_t)(n0 + srow) * K + scol;
    ushort_t* AsW = &As[w * 1024];
    ushort_t* BsW = &Bs[w * 1024];

    floatx4 acc[4][4];
#pragma unroll
    for (int i = 0; i < 4; ++i)
#pragma unroll
        for (int j = 0; j < 4; ++j) acc[i][j] = (floatx4)0.0f;

    for (int k0 = 0; k0 < K; k0 += 32) {
        __syncthreads();
        glds16(Ag + k0,          AsW);
        glds16(Ag + k0 + 16 * K, AsW + 512);
        glds16(Bg + k0,          BsW);
        glds16(Bg + k0 + 16 * K, BsW + 512);
        __syncthreads();
        bf16x8 af[4], bfr[4];
#pragma unroll
        for (int i = 0; i < 4; ++i)
            af[i] = *(const bf16x8*)&As[(wm + i * 16 + c) * 32 + g * 8];
#pragma unroll
        for (int j = 0; j < 4; ++j)
            bfr[j] = *(const bf16x8*)&Bs[(wn + j * 16 + c) * 32 + g * 8];
#pragma unroll
        for (int i = 0; i < 4; ++i)
#pragma unroll
            for (int j = 0; j < 4; ++j)
                acc[i][j] = __builtin_amdgcn_mfma_f32_16x16x32_bf16(
                    af[i], bfr[j], acc[i][j], 0, 0, 0);
    }
#pragma unroll
    for (int i = 0; i < 4; ++i) {
#pragma unroll
        for (int j = 0; j < 4; ++j) {
            const int gc = n0 + wn + j * 16 + c;
            const int gr0 = m0 + wm + i * 16 + g * 4;
            if (tr) {
                // transposed bf16 store: VT[b][gc][n], 4 consecutive n
                u16x4 o4;
#pragma unroll
                for (int r = 0; r < 4; ++r) o4[r] = f2bf(acc[i][j][r]);
                const size_t ti = ((size_t)(gr0 >> 10) << 20)
                                + (size_t)gc * 1024 + (gr0 & 1023);
                *(u16x4*)&((ushort_t*)C)[ti] = o4;
            } else {
#pragma unroll
                for (int r = 0; r < 4; ++r) {
                    const int gr = gr0 + r;
                    float v = acc[i][j][r];
                    if (addraw) {
                        const size_t ai = (size_t)aoff + (size_t)gr * N + gc;
                        const float av = isf ? ((const float*)addraw)[ai]
                                             : bf2f(((const ushort_t*)addraw)[ai]);
                        v += av + bf2f(bias[gc]);
                    }
                    const size_t idx = ooff + (size_t)gr * N + gc;
                    if (f32o) ((float*)C)[idx] = v;
                    else      ((ushort_t*)C)[idx] = f2bf(v);
                }
            }
        }
    }
}

__global__ __launch_bounds__(256) void gemm_proj(
    const ushort_t* __restrict__ ActC, const ushort_t* __restrict__ WT,
    ushort_t* __restrict__ Pbuf, long astride, long pstride)
{
    const int z = blockIdx.z;
    const int asel = (z == 0) ? 0 : (z <= 2 ? 1 : 2);
    // WT order: 0 Wq, 1 Wk_ta, 2 Wk_tv, 3 Wv_ta, 4 Wv_tv, 5 Wout
    const int wsel = (z == 2) ? 3 : ((z == 3) ? 2 : z);
    const bool tr = (z == 2) || (z == 4);   // V projections -> transposed
    gemm_core(ActC + (size_t)asel * astride,
              WT + (size_t)wsel * 1024 * 1024,
              Pbuf + (size_t)z * pstride, 0, false, tr,
              nullptr, 0, nullptr, false);
}

__global__ __launch_bounds__(256) void gemm_out(
    const ushort_t* __restrict__ OutSum, const ushort_t* __restrict__ WoutT,
    const void* __restrict__ hyper_raw, long aoff,
    const ushort_t* __restrict__ boutC,
    void* __restrict__ out, long ooff, const int* __restrict__ flag)
{
    const bool isf = (*flag != 0);
    gemm_core(OutSum, WoutT, out, (size_t)ooff, isf, false,
              hyper_raw, aoff, boutC, isf);
}

// ---------------------------------------------------------------------------
// Fused dual-stream MFMA flash attention, round-15:
//  - swapped QK^T: lane-local softmax rows; shfl 64 -> 16 per kt
//  - Ps stride 68 (measured zero-conflict); b64 P-writes
//  - T13 defer-max THR=8
//  - NEW (single delta vs R10): P-pack via native __bf16 vector cast ->
//    compiler emits v_cvt_pk_bf16_f32 (RNE; identical to f2bf on positive
//    finite values — exp2 output is always positive finite). Cuts ~48
//    packing VALU ops per kt per stream (VALUBusy was 50%, dominant pipe).
//  - V consumed from VT (d-major from gemm_proj)
// ---------------------------------------------------------------------------
__global__ __launch_bounds__(512) void attn_fused(
    const ushort_t* __restrict__ Qb,
    const ushort_t* __restrict__ Kta, const ushort_t* __restrict__ Vta,
    const ushort_t* __restrict__ Ktv, const ushort_t* __restrict__ Vtv,
    ushort_t* __restrict__ Osum)
{
    const int h = blockIdx.x, qb = blockIdx.y, lb = blockIdx.z;
    const int tid = threadIdx.x, w = tid >> 6, lane = tid & 63;
    const int g = lane >> 4, c = lane & 15;

    __shared__ __align__(16) ushort_t Ks[2][64 * 68];   // K tiles [j][d]
    __shared__ __align__(16) ushort_t Vt[2][64 * 68];   // V^T tiles [d][j]
    __shared__ __align__(16) ushort_t Ps[8][16 * 68];   // per-wave P [q][j]

    const float qscale = 0.125f * 1.44269504f;  // SCALE * log2(e)
    const size_t hcol = (size_t)h * 64;
    const size_t kbase = (size_t)lb * 1024;

    // staging coords: 512 threads cover 64 rows x 64 cols in one shot
    const int sj = tid >> 3;            // 0..63
    const int sd = (tid & 7) * 8;       // 0..56

    const ushort_t* Kp[2] = { Kta, Ktv };
    const ushort_t* Vv[2] = { Vta, Vtv };
    // VT row base for this (lb, h): VT[lb][hcol + sj][*]
    const size_t vrow = (size_t)lb * 1048576 + (hcol + sj) * 1024;

    // ---- prefetch kt=0 tiles into registers (in flight during Q setup)
    u32x4 pk[2], pv[2];
#pragma unroll
    for (int s = 0; s < 2; ++s) {
        pk[s] = *(const u32x4*)(Kp[s] + (kbase + sj) * 1024 + hcol + sd);
        pv[s] = *(const u32x4*)(Vv[s] + vrow + sd);
    }

    // ---- stage Q (128 rows) through Ks[0..1]; hoist pre-scaled fragments
    bf16x8 aq[2];
    {
        const size_t qrow0 = kbase + (size_t)qb * 128;
#pragma unroll
        for (int r = 0; r < 2; ++r)
            *(u32x4*)&Ks[r][sj * 68 + sd] =
                *(const u32x4*)(Qb + (qrow0 + r * 64 + sj) * 1024 + hcol + sd);
        __syncthreads();
        const int qbuf = w >> 2, qrow = (w & 3) * 16;
#pragma unroll
        for (int dh = 0; dh < 2; ++dh) {
            u16x8 raw = *(const u16x8*)&Ks[qbuf][(qrow + c) * 68 + dh * 32 + g * 8];
            u16x8 sc;
#pragma unroll
            for (int e = 0; e < 8; ++e) sc[e] = f2bf(bf2f(raw[e]) * qscale);
            aq[dh] = __builtin_bit_cast(bf16x8_b, (u16x8_b)sc);
        }
    }

    floatx4 O[2][4];
    float m[2], l[2];
#pragma unroll
    for (int s = 0; s < 2; ++s) {
#pragma unroll
        for (int dt = 0; dt < 4; ++dt) O[s][dt] = (floatx4)0.0f;
        m[s] = -1e30f; l[s] = 0.0f;
    }

    for (int kt = 0; kt < 16; ++kt) {
        __syncthreads();  // previous tile's LDS reads complete
#pragma unroll
        for (int s = 0; s < 2; ++s) {
            *(u32x4*)&Ks[s][sj * 68 + sd] = pk[s];
            *(u32x4*)&Vt[s][sj * 68 + sd] = pv[s];
        }
        if (kt < 15) {
            const size_t krow0 = kbase + (size_t)(kt + 1) * 64;
#pragma unroll
            for (int s = 0; s < 2; ++s) {
                pk[s] = *(const u32x4*)(Kp[s] + (krow0 + sj) * 1024 + hcol + sd);
                pv[s] = *(const u32x4*)(Vv[s] + vrow + (kt + 1) * 64 + sd);
            }
        }
        __syncthreads();  // tiles visible to all waves

        // ---- QK^T (swapped): S^T[j][q], both streams
        floatx4 S[2][4];
#pragma unroll
        for (int s = 0; s < 2; ++s)
#pragma unroll
            for (int jt = 0; jt < 4; ++jt) S[s][jt] = (floatx4)0.0f;
        __builtin_amdgcn_s_setprio(1);
#pragma unroll
        for (int s = 0; s < 2; ++s)
#pragma unroll
            for (int dh = 0; dh < 2; ++dh)
#pragma unroll
                for (int jt = 0; jt < 4; ++jt) {
                    bf16x8 bk = *(const bf16x8*)&Ks[s][(jt * 16 + c) * 68 + dh * 32 + g * 8];
                    S[s][jt] = __builtin_amdgcn_mfma_f32_16x16x32_bf16(
                        bk, aq[dh], S[s][jt], 0, 0, 0);
                }
        __builtin_amdgcn_s_setprio(0);

        // ---- per stream: lane-local softmax (defer-max) -> Ps (b64) -> PV
#pragma unroll
        for (int s = 0; s < 2; ++s) {
            // tile max over the 16 lane-local j-values + cross-g reduce
            float mx0 = fmaxf(fmaxf(S[s][0][0], S[s][0][1]),
                              fmaxf(S[s][0][2], S[s][0][3]));
            float mx1 = fmaxf(fmaxf(S[s][1][0], S[s][1][1]),
                              fmaxf(S[s][1][2], S[s][1][3]));
            float mx2 = fmaxf(fmaxf(S[s][2][0], S[s][2][1]),
                              fmaxf(S[s][2][2], S[s][2][3]));
            float mx3 = fmaxf(fmaxf(S[s][3][0], S[s][3][1]),
                              fmaxf(S[s][3][2], S[s][3][3]));
            float mx = fmaxf(fmaxf(mx0, mx1), fmaxf(mx2, mx3));
            mx = fmaxf(mx, __shfl_xor(mx, 16));
            mx = fmaxf(mx, __shfl_xor(mx, 32));

            // T13 defer-max: only rescale when the tile max grew past m+8.
            const bool need = !__all(mx - m[s] <= 8.0f);
            float mn = m[s];
            if (need) mn = fmaxf(m[s], mx);

            float rs = 0.0f;
#pragma unroll
            for (int jt = 0; jt < 4; ++jt) {
                bf16x4 pp;
#pragma unroll
                for (int r = 0; r < 4; ++r) {
                    const float p = __builtin_amdgcn_exp2f(S[s][jt][r] - mn);
                    rs += p;
                    pp[r] = (bf16_t)p;   // v_cvt_pk_bf16_f32 (RNE)
                }
                *(bf16x4*)&Ps[w][c * 68 + jt * 16 + g * 4] = pp;
            }
            rs += __shfl_xor(rs, 16);
            rs += __shfl_xor(rs, 32);

            if (need) {
                const float al = __builtin_amdgcn_exp2f(m[s] - mn);
                m[s] = mn;
                l[s] = l[s] * al + rs;
                float alq[4];
#pragma unroll
                for (int r = 0; r < 4; ++r) alq[r] = __shfl(al, g * 4 + r);
#pragma unroll
                for (int dt = 0; dt < 4; ++dt)
#pragma unroll
                    for (int r = 0; r < 4; ++r) O[s][dt][r] *= alq[r];
            } else {
                l[s] += rs;
            }

            // PV: A = P[q=c][j-slice], B = V^T[d=c][j-slice]
#pragma unroll
            for (int jh = 0; jh < 2; ++jh) {
                bf16x8 ap = *(const bf16x8*)&Ps[w][c * 68 + jh * 32 + g * 8];
                __builtin_amdgcn_s_setprio(1);
#pragma unroll
                for (int dt = 0; dt < 4; ++dt) {
                    bf16x8 bv = *(const bf16x8*)&Vt[s][(dt * 16 + c) * 68
                                                      + jh * 32 + g * 8];
                    O[s][dt] = __builtin_amdgcn_mfma_f32_16x16x32_bf16(
                        ap, bv, O[s][dt], 0, 0, 0);
                }
                __builtin_amdgcn_s_setprio(0);
            }
        }
    }

    // ---- epilogue: transport l to O-row layout; Osum = O_ta/l + O_tv/l
    float lq0[4], lq1[4];
#pragma unroll
    for (int r = 0; r < 4; ++r) {
        lq0[r] = __shfl(l[0], g * 4 + r);
        lq1[r] = __shfl(l[1], g * 4 + r);
    }
    const size_t orow0 = kbase + (size_t)qb * 128 + w * 16;
#pragma unroll
    for (int dt = 0; dt < 4; ++dt)
#pragma unroll
        for (int r = 0; r < 4; ++r) {
            const float v = O[0][dt][r] / lq0[r] + O[1][dt][r] / lq1[r];
            Osum[(orow0 + g * 4 + r) * 1024 + hcol + dt * 16 + c] = f2bf(v);
        }
}

// ---------------------------------------------------------------------------
extern "C" void kernel_launch(void* const* d_in, const int* in_sizes, int n_in,
                              void* d_out, int out_size, void* d_ws, size_t ws_size,
                              hipStream_t stream)
{
    const void* h_t     = d_in[0];
    const void* h_a     = d_in[1];
    const void* h_v     = d_in[2];
    const void* h_hyper = d_in[3];
    const void* Wq      = d_in[4];
    const void* Wk_ta   = d_in[5];
    const void* Wk_tv   = d_in[6];
    const void* Wv_ta   = d_in[7];
    const void* Wv_tv   = d_in[8];
    const void* Wout    = d_in[9];
    const void* bout    = d_in[10];

    constexpr size_t MEG = (size_t)1024 * 1024;
    // header: flag at elem 0, boutC at elem 1024; payload starts at elem 4096
    int*      flag  = (int*)d_ws;
    ushort_t* boutC = (ushort_t*)d_ws + 1024;
    ushort_t* WT    = (ushort_t*)d_ws + 4096;

    detect_dtype<<<1, 256, 0, stream>>>((const unsigned int*)h_t, flag);
    conv_weights<<<dim3(16, 16, 6), 256, 0, stream>>>(
        Wq, Wk_ta, Wk_tv, Wv_ta, Wv_tv, Wout, WT, flag);
    conv_bout<<<1, 256, 0, stream>>>(bout, boutC, flag);

    // merged path needs: 4096 + 6M(WT) + 24M(ActC) + 40M(Pbuf) elements
    const size_t need_merged = (4096 + 70 * MEG) * sizeof(ushort_t);

    if (ws_size >= need_merged) {
        // ---- single pass over all 8 batches ----
        ushort_t* ActC = WT + 6 * MEG;          // 3 x 8M (h_t,h_a,h_v bf16)
        ushort_t* Pbuf = ActC + 24 * MEG;       // 5 x 8M projections
        ushort_t* OSg  = ActC;                  // alias: ActC dead after proj

        conv_act<<<dim3(4096, 3), 256, 0, stream>>>(
            h_t, h_a, h_v, 0, ActC, (long)(8 * MEG), flag);
        gemm_proj<<<dim3(64, 8, 5), 256, 0, stream>>>(
            ActC, WT, Pbuf, (long)(8 * MEG), (long)(8 * MEG));
        attn_fused<<<dim3(16, 8, 8), 512, 0, stream>>>(
            Pbuf,
            Pbuf + 8 * MEG,  Pbuf + 16 * MEG,
            Pbuf + 24 * MEG, Pbuf + 32 * MEG,
            OSg);
        gemm_out<<<dim3(64, 8), 256, 0, stream>>>(
            OSg, WT + 5 * MEG, h_hyper, 0, boutC, d_out, 0, flag);
    } else {
        // ---- fallback: 4 groups of 2 batches (same kernels, smaller grid) ----
        ushort_t* ActC = WT + 6 * MEG;          // 3 x 2M
        ushort_t* Pbuf = ActC + 6 * MEG;        // 5 x 2M
        ushort_t* OSg  = ActC;                  // alias: ActC dead after proj
        const long GSTRIDE = 2 * 1024 * 1024;
        for (int grp = 0; grp < 4; ++grp) {
            const long off = (long)grp * GSTRIDE;
            conv_act<<<dim3(1024, 3), 256, 0, stream>>>(
                h_t, h_a, h_v, off, ActC, (long)(2 * MEG), flag);
            gemm_proj<<<dim3(16, 8, 5), 256, 0, stream>>>(
                ActC, WT, Pbuf, (long)(2 * MEG), (long)(2 * MEG));
            attn_fused<<<dim3(16, 8, 2), 512, 0, stream>>>(
                Pbuf,
                Pbuf + 2 * MEG, Pbuf + 4 * MEG,
                Pbuf + 6 * MEG, Pbuf + 8 * MEG,
                OSg);
            gemm_out<<<dim3(16, 8), 256, 0, stream>>>(
                OSg, WT + 5 * MEG, h_hyper, off, boutC, d_out, off, flag);
        }
    }
}